// Round 16
// baseline (760.672 us; speedup 1.0000x reference)
//
#include <hip/hip_runtime.h>

#define M_DIM 65536
#define K_DIM 2048
#define N_DIM 1024
#define EPSV 1e-5f

typedef __bf16 bf16;
typedef bf16 bf16x8 __attribute__((ext_vector_type(8)));
typedef bf16 bf16x4 __attribute__((ext_vector_type(4)));
typedef float f32x4 __attribute__((ext_vector_type(4)));

// monotone float <-> uint encoding for atomicMin on float
__device__ inline unsigned fenc(float f) {
    unsigned u = __float_as_uint(f);
    return (u & 0x80000000u) ? ~u : (u | 0x80000000u);
}
__device__ inline float fdec(unsigned e) {
    unsigned u = (e & 0x80000000u) ? (e & 0x7fffffffu) : ~e;
    return __uint_as_float(u);
}

__device__ __forceinline__ void gload_lds16(const bf16* g, bf16* l) {
    __builtin_amdgcn_global_load_lds(
        (const __attribute__((address_space(1))) unsigned int*)g,
        (__attribute__((address_space(3))) unsigned int*)l, 16, 0, 0);
}

// fp32 -> bf16 conversion (W only: 4 MB, ~2 us)
__global__ void cvt_kernel(const float* __restrict__ in, bf16* __restrict__ out, long n4) {
    long i = (long)blockIdx.x * blockDim.x + threadIdx.x;
    long stride = (long)gridDim.x * blockDim.x;
    for (; i < n4; i += stride) {
        f32x4 v = ((const f32x4*)in)[i];
        bf16x4 h;
        h[0] = (bf16)v[0]; h[1] = (bf16)v[1]; h[2] = (bf16)v[2]; h[3] = (bf16)v[3];
        ((bf16x4*)out)[i] = h;
    }
}

// R15 + A-PREFETCH: 128x128, BK=64, 4 waves, 32 KB LDS -> ~4 blocks/CU
// (cross-block DS/MFMA overlap), conflict-free XOR swizzle, XCD swizzle.
// A is staged from FP32 x with DOUBLE-BUFFERED registers: the fp32 loads
// for tile kt+1 are issued inside tile kt's MFMA region and consumed one
// iteration later (>=1 phase old => latency hidden). Barrier discipline:
//   barrier-1 (pre-MFMA):  vmcnt(0)+lgkmcnt(0) — drains B-DMA + A writes.
//     At this point the A-prefetch is already register-retired (cvt deps),
//     so vmcnt(0) is exact, not an over-drain.
//   barrier-2 (post-MFMA): lgkmcnt(0) ONLY — ds_reads are complete, and
//     the in-flight A-prefetch SURVIVES the barrier (the __syncthreads
//     vmcnt(0) drain is what killed R15's overlap).
// WAR on the prefetch buffer is safe: consumed a full iteration earlier.
__global__ void gemm_fused(const float* __restrict__ X, const bf16* __restrict__ Wb,
                           const float* __restrict__ gnw, const float* __restrict__ gnb,
                           unsigned* __restrict__ rowmin) {
    __shared__ __align__(16) bf16 As[128][64];
    __shared__ __align__(16) bf16 Bs[128][64];

    const int tid = threadIdx.x;
    const int wave = tid >> 6, lane = tid & 63;
    const int wr = wave >> 1, wc = wave & 1;   // 2 x 2 wave grid
    const int q = lane >> 4, r = lane & 15;

    // T1: bijective XCD-chunked swizzle (4096 blocks % 8 == 0); chunk of
    // 512 consecutive swz per XCD = 64 by x 8 bx; bx fastest -> fp32
    // A-panel read from HBM ~once per by per XCD, re-served by L2.
    const int bid = blockIdx.x;
    const int swz = (bid & 7) * 512 + (bid >> 3);
    const int bx = swz & 7, by = swz >> 3;
    const int brow = by * 128, bcol = bx * 128;

    const float* Arowf = X + (size_t)brow * K_DIM;
    const bf16* Brow = Wb + (size_t)bcol * K_DIM;

    f32x4 acc[4][4];
#pragma unroll
    for (int m = 0; m < 4; ++m)
#pragma unroll
        for (int n = 0; n < 4; ++n) acc[m][n] = 0.0f;

    // read-side swizzled granule offsets (bf16 units), per kk half
    const int r7 = r & 7;
    const int ga0 = ((0 + q) ^ r7) * 8;   // kk = 0
    const int ga1 = ((4 + q) ^ r7) * 8;   // kk = 32
    const int arow_l = wr * 64 + r;       // + m*16
    const int brow_l = wc * 64 + r;       // + n*16

    f32x4 va[8], vb[8];  // double-buffered in-flight fp32 A granules

#define A_PREFETCH(BUF, KT) do {                                                  \
        const int kp = ((KT) & 31) * 64;                                          \
        _Pragma("unroll") for (int j = 0; j < 4; ++j) {                           \
            int gi = j * 256 + tid;                                               \
            int row = gi >> 3, g = gi & 7;                                        \
            const float* src = Arowf + (size_t)row * K_DIM + kp + g * 8;          \
            BUF[2 * j]     = *(const f32x4*)(src);                                \
            BUF[2 * j + 1] = *(const f32x4*)(src + 4);                            \
        }                                                                         \
    } while (0)

    // One K-tile: consume CUR (cvt+swizzled ds_write), B via gload_lds,
    // MFMA, and prefetch NXT <- tile KT+1 inside the MFMA region.
#define TILE_ITER(CUR, NXT, KT) do {                                              \
        const int k0 = (KT) * 64;                                                 \
        /* B: gload_lds + source-side swizzle (oldest VMEM this iter) */          \
        _Pragma("unroll") for (int i = 0; i < 4; ++i) {                           \
            int chunk = i * 256 + tid;                                            \
            int row = chunk >> 3, g = chunk & 7;                                  \
            int gsw = g ^ (row & 7);                                              \
            gload_lds16(Brow + (size_t)row * K_DIM + k0 + gsw * 8,                \
                        &Bs[0][0] + (size_t)(i * 256 + (tid & 192)) * 8);         \
        }                                                                         \
        /* A: convert CUR + swizzled ds_write (register deps retire CUR) */       \
        _Pragma("unroll") for (int j = 0; j < 4; ++j) {                           \
            int gi = j * 256 + tid;                                               \
            int row = gi >> 3, g = gi & 7;                                        \
            bf16x8 h;                                                             \
            h[0] = (bf16)CUR[2 * j][0];     h[1] = (bf16)CUR[2 * j][1];           \
            h[2] = (bf16)CUR[2 * j][2];     h[3] = (bf16)CUR[2 * j][3];           \
            h[4] = (bf16)CUR[2 * j + 1][0]; h[5] = (bf16)CUR[2 * j + 1][1];       \
            h[6] = (bf16)CUR[2 * j + 1][2]; h[7] = (bf16)CUR[2 * j + 1][3];       \
            *(bf16x8*)(&As[0][0] + (size_t)row * 64 +                             \
                       (size_t)(g ^ (row & 7)) * 8) = h;                          \
        }                                                                         \
        /* barrier-1: drain B-DMA (vmcnt: only B outstanding) + A writes */       \
        asm volatile("s_waitcnt vmcnt(0) lgkmcnt(0)" ::: "memory");               \
        __builtin_amdgcn_s_barrier();                                             \
        asm volatile("" ::: "memory");                                            \
        /* MFMA region: prefetch NXT first, then reads + MFMAs */                 \
        A_PREFETCH(NXT, (KT) + 1);                                                \
        _Pragma("unroll") for (int kk = 0; kk < 2; ++kk) {                        \
            const int ga = kk ? ga1 : ga0;                                        \
            bf16x8 a[4], b[4];                                                    \
            _Pragma("unroll") for (int m = 0; m < 4; ++m)                         \
                a[m] = *(const bf16x8*)(&As[0][0] + (arow_l + m * 16) * 64 + ga); \
            _Pragma("unroll") for (int n = 0; n < 4; ++n)                         \
                b[n] = *(const bf16x8*)(&Bs[0][0] + (brow_l + n * 16) * 64 + ga); \
            _Pragma("unroll") for (int m = 0; m < 4; ++m)                         \
                _Pragma("unroll") for (int n = 0; n < 4; ++n)                     \
                    acc[m][n] = __builtin_amdgcn_mfma_f32_16x16x32_bf16(          \
                        a[m], b[n], acc[m][n], 0, 0, 0);                          \
        }                                                                         \
        /* barrier-2: lgkm only — A-prefetch stays in flight */                   \
        asm volatile("s_waitcnt lgkmcnt(0)" ::: "memory");                        \
        __builtin_amdgcn_s_barrier();                                             \
        asm volatile("" ::: "memory");                                            \
    } while (0)

    // ---- prologue: load tile 0's fp32 A into va ----
    A_PREFETCH(va, 0);

    // ---- main loop: 32 K-tiles, parity-unrolled ----
    for (int kt2 = 0; kt2 < 16; ++kt2) {
        TILE_ITER(va, vb, 2 * kt2);
        TILE_ITER(vb, va, 2 * kt2 + 1);   // kt=31 prefetches tile 0 (unused)
    }

    // ---- fused epilogue: GroupNorm (group == wave's 64-col span) + row min ----
    float gw[4], gb[4];
#pragma unroll
    for (int n = 0; n < 4; ++n) {
        int col = bcol + wc * 64 + n * 16 + r;
        gw[n] = gnw[col];
        gb[n] = gnb[col];
    }
#pragma unroll
    for (int m = 0; m < 4; ++m) {
#pragma unroll
        for (int j = 0; j < 4; ++j) {
            float s = 0.f, ss = 0.f;
#pragma unroll
            for (int n = 0; n < 4; ++n) {
                float v = acc[m][n][j];
                s += v; ss += v * v;
            }
#pragma unroll
            for (int d = 1; d < 16; d <<= 1) {
                s += __shfl_xor(s, d);
                ss += __shfl_xor(ss, d);
            }
            float mean = s * (1.f / 64.f);
            float var = ss * (1.f / 64.f) - mean * mean;
            float rstd = rsqrtf(var + EPSV);
            float mn = 3.4e38f;
#pragma unroll
            for (int n = 0; n < 4; ++n) {
                float y = (acc[m][n][j] - mean) * rstd * gw[n] + gb[n];
                mn = fminf(mn, y);
            }
#pragma unroll
            for (int d = 1; d < 16; d <<= 1) mn = fminf(mn, __shfl_xor(mn, d));
            if (r == 0)
                atomicMin(&rowmin[brow + wr * 64 + m * 16 + q * 4 + j], fenc(mn));
        }
    }
}

// out[m][n] = dec(rowmin[m]) + bias[n]
__global__ void bcast_kernel(const unsigned* __restrict__ rowmin,
                             const float* __restrict__ bias,
                             float* __restrict__ out) {
    const long total4 = (long)M_DIM * N_DIM / 4;
    long i = (long)blockIdx.x * blockDim.x + threadIdx.x;
    long stride = (long)gridDim.x * blockDim.x;
    for (; i < total4; i += stride) {
        int mrow = (int)(i >> 8);  // N/4 = 256 float4 per row
        int n4 = (int)(i & 255);
        float rm = fdec(rowmin[mrow]);
        f32x4 b = ((const f32x4*)bias)[n4];
        f32x4 o;
        o[0] = rm + b[0]; o[1] = rm + b[1]; o[2] = rm + b[2]; o[3] = rm + b[3];
        ((f32x4*)out)[i] = o;
    }
}

extern "C" void kernel_launch(void* const* d_in, const int* in_sizes, int n_in,
                              void* d_out, int out_size, void* d_ws, size_t ws_size,
                              hipStream_t stream) {
    const float* x = (const float*)d_in[0];
    const float* w = (const float*)d_in[1];
    const float* gnw = (const float*)d_in[2];
    const float* gnb = (const float*)d_in[3];
    const float* bias = (const float*)d_in[4];

    unsigned char* ws = (unsigned char*)d_ws;
    unsigned* rowmin = (unsigned*)ws;                          // 256 KB
    bf16* wb = (bf16*)(ws + (size_t)M_DIM * 4);                // 4 MB

    (void)hipMemsetAsync(rowmin, 0xFF, (size_t)M_DIM * 4, stream);  // +inf in encoding
    cvt_kernel<<<512, 256, 0, stream>>>(w, wb, (long)N_DIM * K_DIM / 4);

    gemm_fused<<<dim3(4096), 256, 0, stream>>>(x, wb, gnw, gnb, rowmin);

    bcast_kernel<<<2048, 256, 0, stream>>>(rowmin, bias, (float*)d_out);
}

// Round 17
// 495.618 us; speedup vs baseline: 1.5348x; 1.5348x over previous
//
#include <hip/hip_runtime.h>

#define M_DIM 65536
#define K_DIM 2048
#define N_DIM 1024
#define EPSV 1e-5f

typedef __bf16 bf16;
typedef bf16 bf16x8 __attribute__((ext_vector_type(8)));
typedef bf16 bf16x4 __attribute__((ext_vector_type(4)));
typedef float f32x4 __attribute__((ext_vector_type(4)));

// monotone float <-> uint encoding for atomicMin on float
__device__ inline unsigned fenc(float f) {
    unsigned u = __float_as_uint(f);
    return (u & 0x80000000u) ? ~u : (u | 0x80000000u);
}
__device__ inline float fdec(unsigned e) {
    unsigned u = (e & 0x80000000u) ? (e & 0x7fffffffu) : ~e;
    return __uint_as_float(u);
}

__device__ __forceinline__ void gload_lds16(const bf16* g, bf16* l) {
    __builtin_amdgcn_global_load_lds(
        (const __attribute__((address_space(1))) unsigned int*)g,
        (__attribute__((address_space(3))) unsigned int*)l, 16, 0, 0);
}

// fp32 -> bf16 conversion (W only: 4 MB, ~2 us)
__global__ void cvt_kernel(const float* __restrict__ in, bf16* __restrict__ out, long n4) {
    long i = (long)blockIdx.x * blockDim.x + threadIdx.x;
    long stride = (long)gridDim.x * blockDim.x;
    for (; i < n4; i += stride) {
        f32x4 v = ((const f32x4*)in)[i];
        bf16x4 h;
        h[0] = (bf16)v[0]; h[1] = (bf16)v[1]; h[2] = (bf16)v[2]; h[3] = (bf16)v[3];
        ((bf16x4*)out)[i] = h;
    }
}

// R16 pipeline, SINGLE-buffered prefetch + explicit register budget.
// 128x128, BK=64, 4 waves, 32 KB LDS; conflict-free XOR swizzle; XCD
// swizzle. A staged from FP32 x with a one-iteration register prefetch:
//   iter kt: [B gload_lds] [cvt va -> swizzled ds_write (va = tile kt,
//   loaded one iter ago)] [barrier-1: vmcnt(0)+lgkm(0) — exact: only the
//   B-DMA is outstanding, va already register-retired] [MFMA region:
//   refill va <- tile kt+1 (WAR legal in-order; completes across
//   barrier-2 before next use) + ds_reads + 32 MFMA] [barrier-2: lgkm
//   ONLY — refill survives the barrier].
// R16's failure was scratch-spill of the 64-VGPR double buffer (WRITE_SIZE
// 378 MB). Single buffer (32 VGPR) + __launch_bounds__(256,3) (cap ~170
// VGPR, 3 blocks/CU) keeps the allocator in registers: budget acc 64 +
// va 32 + frags 32 + addr ~20 = ~150 < 170.
__global__ __launch_bounds__(256, 3)
void gemm_fused(const float* __restrict__ X, const bf16* __restrict__ Wb,
                const float* __restrict__ gnw, const float* __restrict__ gnb,
                unsigned* __restrict__ rowmin) {
    __shared__ __align__(16) bf16 As[128][64];
    __shared__ __align__(16) bf16 Bs[128][64];

    const int tid = threadIdx.x;
    const int wave = tid >> 6, lane = tid & 63;
    const int wr = wave >> 1, wc = wave & 1;   // 2 x 2 wave grid
    const int q = lane >> 4, r = lane & 15;

    // T1: bijective XCD-chunked swizzle (4096 blocks % 8 == 0)
    const int bid = blockIdx.x;
    const int swz = (bid & 7) * 512 + (bid >> 3);
    const int bx = swz & 7, by = swz >> 3;
    const int brow = by * 128, bcol = bx * 128;

    const float* Arowf = X + (size_t)brow * K_DIM;
    const bf16* Brow = Wb + (size_t)bcol * K_DIM;

    f32x4 acc[4][4];
#pragma unroll
    for (int m = 0; m < 4; ++m)
#pragma unroll
        for (int n = 0; n < 4; ++n) acc[m][n] = 0.0f;

    // read-side swizzled granule offsets (bf16 units), per kk half
    const int r7 = r & 7;
    const int ga0 = ((0 + q) ^ r7) * 8;   // kk = 0
    const int ga1 = ((4 + q) ^ r7) * 8;   // kk = 32
    const int arow_l = wr * 64 + r;       // + m*16
    const int brow_l = wc * 64 + r;       // + n*16

    f32x4 va[8];  // single in-flight fp32 A buffer (statically indexed)

#define A_PREFETCH(KT) do {                                                       \
        const int kp = ((KT) & 31) * 64;                                          \
        _Pragma("unroll") for (int j = 0; j < 4; ++j) {                           \
            int gi = j * 256 + tid;                                               \
            int row = gi >> 3, g = gi & 7;                                        \
            const float* src = Arowf + (size_t)row * K_DIM + kp + g * 8;          \
            va[2 * j]     = *(const f32x4*)(src);                                 \
            va[2 * j + 1] = *(const f32x4*)(src + 4);                             \
        }                                                                         \
    } while (0)

#define TILE_ITER(KT) do {                                                        \
        const int k0 = (KT) * 64;                                                 \
        /* B: gload_lds + source-side swizzle */                                  \
        _Pragma("unroll") for (int i = 0; i < 4; ++i) {                           \
            int chunk = i * 256 + tid;                                            \
            int row = chunk >> 3, g = chunk & 7;                                  \
            int gsw = g ^ (row & 7);                                              \
            gload_lds16(Brow + (size_t)row * K_DIM + k0 + gsw * 8,                \
                        &Bs[0][0] + (size_t)(i * 256 + (tid & 192)) * 8);         \
        }                                                                         \
        /* A: convert va (tile KT, one iter old) + swizzled ds_write */           \
        _Pragma("unroll") for (int j = 0; j < 4; ++j) {                           \
            int gi = j * 256 + tid;                                               \
            int row = gi >> 3, g = gi & 7;                                        \
            bf16x8 h;                                                             \
            h[0] = (bf16)va[2 * j][0];     h[1] = (bf16)va[2 * j][1];             \
            h[2] = (bf16)va[2 * j][2];     h[3] = (bf16)va[2 * j][3];             \
            h[4] = (bf16)va[2 * j + 1][0]; h[5] = (bf16)va[2 * j + 1][1];         \
            h[6] = (bf16)va[2 * j + 1][2]; h[7] = (bf16)va[2 * j + 1][3];         \
            *(bf16x8*)(&As[0][0] + (size_t)row * 64 +                             \
                       (size_t)(g ^ (row & 7)) * 8) = h;                          \
        }                                                                         \
        /* barrier-1: drain B-DMA + A ds_writes (exact) */                        \
        asm volatile("s_waitcnt vmcnt(0) lgkmcnt(0)" ::: "memory");               \
        __builtin_amdgcn_s_barrier();                                             \
        asm volatile("" ::: "memory");                                            \
        /* MFMA region: refill va <- tile KT+1, then reads + MFMAs */             \
        A_PREFETCH((KT) + 1);                                                     \
        _Pragma("unroll") for (int kk = 0; kk < 2; ++kk) {                        \
            const int ga = kk ? ga1 : ga0;                                        \
            bf16x8 a[4], b[4];                                                    \
            _Pragma("unroll") for (int m = 0; m < 4; ++m)                         \
                a[m] = *(const bf16x8*)(&As[0][0] + (arow_l + m * 16) * 64 + ga); \
            _Pragma("unroll") for (int n = 0; n < 4; ++n)                         \
                b[n] = *(const bf16x8*)(&Bs[0][0] + (brow_l + n * 16) * 64 + ga); \
            _Pragma("unroll") for (int m = 0; m < 4; ++m)                         \
                _Pragma("unroll") for (int n = 0; n < 4; ++n)                     \
                    acc[m][n] = __builtin_amdgcn_mfma_f32_16x16x32_bf16(          \
                        a[m], b[n], acc[m][n], 0, 0, 0);                          \
        }                                                                         \
        /* barrier-2: lgkm only — va refill stays in flight */                    \
        asm volatile("s_waitcnt lgkmcnt(0)" ::: "memory");                        \
        __builtin_amdgcn_s_barrier();                                             \
        asm volatile("" ::: "memory");                                            \
    } while (0)

    // ---- prologue: load tile 0's fp32 A into va ----
    A_PREFETCH(0);

    // ---- main loop: 32 K-tiles ----
    for (int kt = 0; kt < 32; ++kt) {
        TILE_ITER(kt);   // kt=31 refills tile 0 (unused)
    }

    // ---- fused epilogue: GroupNorm (group == wave's 64-col span) + row min ----
    float gw[4], gb[4];
#pragma unroll
    for (int n = 0; n < 4; ++n) {
        int col = bcol + wc * 64 + n * 16 + r;
        gw[n] = gnw[col];
        gb[n] = gnb[col];
    }
#pragma unroll
    for (int m = 0; m < 4; ++m) {
#pragma unroll
        for (int j = 0; j < 4; ++j) {
            float s = 0.f, ss = 0.f;
#pragma unroll
            for (int n = 0; n < 4; ++n) {
                float v = acc[m][n][j];
                s += v; ss += v * v;
            }
#pragma unroll
            for (int d = 1; d < 16; d <<= 1) {
                s += __shfl_xor(s, d);
                ss += __shfl_xor(ss, d);
            }
            float mean = s * (1.f / 64.f);
            float var = ss * (1.f / 64.f) - mean * mean;
            float rstd = rsqrtf(var + EPSV);
            float mn = 3.4e38f;
#pragma unroll
            for (int n = 0; n < 4; ++n) {
                float y = (acc[m][n][j] - mean) * rstd * gw[n] + gb[n];
                mn = fminf(mn, y);
            }
#pragma unroll
            for (int d = 1; d < 16; d <<= 1) mn = fminf(mn, __shfl_xor(mn, d));
            if (r == 0)
                atomicMin(&rowmin[brow + wr * 64 + m * 16 + q * 4 + j], fenc(mn));
        }
    }
}

// out[m][n] = dec(rowmin[m]) + bias[n]
__global__ void bcast_kernel(const unsigned* __restrict__ rowmin,
                             const float* __restrict__ bias,
                             float* __restrict__ out) {
    const long total4 = (long)M_DIM * N_DIM / 4;
    long i = (long)blockIdx.x * blockDim.x + threadIdx.x;
    long stride = (long)gridDim.x * blockDim.x;
    for (; i < total4; i += stride) {
        int mrow = (int)(i >> 8);  // N/4 = 256 float4 per row
        int n4 = (int)(i & 255);
        float rm = fdec(rowmin[mrow]);
        f32x4 b = ((const f32x4*)bias)[n4];
        f32x4 o;
        o[0] = rm + b[0]; o[1] = rm + b[1]; o[2] = rm + b[2]; o[3] = rm + b[3];
        ((f32x4*)out)[i] = o;
    }
}

extern "C" void kernel_launch(void* const* d_in, const int* in_sizes, int n_in,
                              void* d_out, int out_size, void* d_ws, size_t ws_size,
                              hipStream_t stream) {
    const float* x = (const float*)d_in[0];
    const float* w = (const float*)d_in[1];
    const float* gnw = (const float*)d_in[2];
    const float* gnb = (const float*)d_in[3];
    const float* bias = (const float*)d_in[4];

    unsigned char* ws = (unsigned char*)d_ws;
    unsigned* rowmin = (unsigned*)ws;                          // 256 KB
    bf16* wb = (bf16*)(ws + (size_t)M_DIM * 4);                // 4 MB

    (void)hipMemsetAsync(rowmin, 0xFF, (size_t)M_DIM * 4, stream);  // +inf in encoding
    cvt_kernel<<<512, 256, 0, stream>>>(w, wb, (long)N_DIM * K_DIM / 4);

    gemm_fused<<<dim3(4096), 256, 0, stream>>>(x, wb, gnw, gnb, rowmin);

    bcast_kernel<<<2048, 256, 0, stream>>>(rowmin, bias, (float*)d_out);
}

// Round 19
// 470.593 us; speedup vs baseline: 1.6164x; 1.0532x over previous
//
#include <hip/hip_runtime.h>

#define M_DIM 65536
#define K_DIM 2048
#define N_DIM 1024
#define EPSV 1e-5f

typedef __bf16 bf16;
typedef bf16 bf16x8 __attribute__((ext_vector_type(8)));
typedef bf16 bf16x4 __attribute__((ext_vector_type(4)));
typedef float f32x4 __attribute__((ext_vector_type(4)));

// monotone float <-> uint encoding for atomicMin on float
__device__ inline unsigned fenc(float f) {
    unsigned u = __float_as_uint(f);
    return (u & 0x80000000u) ? ~u : (u | 0x80000000u);
}
__device__ inline float fdec(unsigned e) {
    unsigned u = (e & 0x80000000u) ? (e & 0x7fffffffu) : ~e;
    return __uint_as_float(u);
}

__device__ __forceinline__ void gload_lds16(const bf16* g, bf16* l) {
    __builtin_amdgcn_global_load_lds(
        (const __attribute__((address_space(1))) unsigned int*)g,
        (__attribute__((address_space(3))) unsigned int*)l, 16, 0, 0);
}

// fp32 -> bf16 conversion (W only: 4 MB, ~2 us)
__global__ void cvt_kernel(const float* __restrict__ in, bf16* __restrict__ out, long n4) {
    long i = (long)blockIdx.x * blockDim.x + threadIdx.x;
    long stride = (long)gridDim.x * blockDim.x;
    for (; i < n4; i += stride) {
        f32x4 v = ((const f32x4*)in)[i];
        bf16x4 h;
        h[0] = (bf16)v[0]; h[1] = (bf16)v[1]; h[2] = (bf16)v[2]; h[3] = (bf16)v[3];
        ((bf16x4*)out)[i] = h;
    }
}

// R18 + ISSUE-ORDER PIN. 128x128, BK=64, 4 waves, 32 KB LDS, conflict-
// free XOR swizzle, XCD swizzle, A staged from FP32 x with full-iteration
// register prefetch. Schedule per iter kt:
//   [B: 4x gload_lds (tile kt)]
//   sched_barrier(0)  <-- THE R18 FIX: guarantees B loads are EMITTED
//       before the A-prefetch loads, so the vmcnt FIFO ledger below is
//       exact. (R18 let the scheduler hoist A loads above B -> vmcnt(8)
//       left B pending -> stale Bs -> absmax 1.5.)
//   [A: cvt va (tile kt, loaded LAST iter) -> swizzled ds_write]
//   [A_PREFETCH(kt+1): 8 fp32 loads -> va]
//   barrier-1: vmcnt(8)+lgkm(0) — outstanding = 4 B (oldest) + 8 A;
//       drains exactly B, keeps the A-prefetch in flight
//   [MFMA region: ds_reads + 32 MFMA]
//   barrier-2: lgkm(0) only — prefetch survives; consumed next iter
//       ~1500 cyc after issue >> 900 cyc HBM.
// Single va buffer (32 VGPR) + launch_bounds(256,3): no spill (R17: VGPR
// 76, WRITE 16 MB).
__global__ __launch_bounds__(256, 3)
void gemm_fused(const float* __restrict__ X, const bf16* __restrict__ Wb,
                const float* __restrict__ gnw, const float* __restrict__ gnb,
                unsigned* __restrict__ rowmin) {
    __shared__ __align__(16) bf16 As[128][64];
    __shared__ __align__(16) bf16 Bs[128][64];

    const int tid = threadIdx.x;
    const int wave = tid >> 6, lane = tid & 63;
    const int wr = wave >> 1, wc = wave & 1;   // 2 x 2 wave grid
    const int q = lane >> 4, r = lane & 15;

    // T1: bijective XCD-chunked swizzle (4096 blocks % 8 == 0)
    const int bid = blockIdx.x;
    const int swz = (bid & 7) * 512 + (bid >> 3);
    const int bx = swz & 7, by = swz >> 3;
    const int brow = by * 128, bcol = bx * 128;

    const float* Arowf = X + (size_t)brow * K_DIM;
    const bf16* Brow = Wb + (size_t)bcol * K_DIM;

    f32x4 acc[4][4];
#pragma unroll
    for (int m = 0; m < 4; ++m)
#pragma unroll
        for (int n = 0; n < 4; ++n) acc[m][n] = 0.0f;

    // read-side swizzled granule offsets (bf16 units), per kk half
    const int r7 = r & 7;
    const int ga0 = ((0 + q) ^ r7) * 8;   // kk = 0
    const int ga1 = ((4 + q) ^ r7) * 8;   // kk = 32
    const int arow_l = wr * 64 + r;       // + m*16
    const int brow_l = wc * 64 + r;       // + n*16

    f32x4 va[8];  // single in-flight fp32 A buffer (statically indexed)

#define A_PREFETCH(KT) do {                                                       \
        const int kp = ((KT) & 31) * 64;                                          \
        _Pragma("unroll") for (int j = 0; j < 4; ++j) {                           \
            int gi = j * 256 + tid;                                               \
            int row = gi >> 3, g = gi & 7;                                        \
            const float* src = Arowf + (size_t)row * K_DIM + kp + g * 8;          \
            va[2 * j]     = *(const f32x4*)(src);                                 \
            va[2 * j + 1] = *(const f32x4*)(src + 4);                             \
        }                                                                         \
    } while (0)

#define TILE_ITER(KT) do {                                                        \
        const int k0 = (KT) * 64;                                                 \
        /* B: gload_lds + source-side swizzle (4 loads, MUST be oldest) */        \
        _Pragma("unroll") for (int i = 0; i < 4; ++i) {                           \
            int chunk = i * 256 + tid;                                            \
            int row = chunk >> 3, g = chunk & 7;                                  \
            int gsw = g ^ (row & 7);                                              \
            gload_lds16(Brow + (size_t)row * K_DIM + k0 + gsw * 8,                \
                        &Bs[0][0] + (size_t)(i * 256 + (tid & 192)) * 8);         \
        }                                                                         \
        __builtin_amdgcn_sched_barrier(0);  /* pin: B before A-prefetch */        \
        /* A: convert va (tile KT, loaded last iter) + swizzled ds_write */       \
        _Pragma("unroll") for (int j = 0; j < 4; ++j) {                           \
            int gi = j * 256 + tid;                                               \
            int row = gi >> 3, g = gi & 7;                                        \
            bf16x8 h;                                                             \
            h[0] = (bf16)va[2 * j][0];     h[1] = (bf16)va[2 * j][1];             \
            h[2] = (bf16)va[2 * j][2];     h[3] = (bf16)va[2 * j][3];             \
            h[4] = (bf16)va[2 * j + 1][0]; h[5] = (bf16)va[2 * j + 1][1];         \
            h[6] = (bf16)va[2 * j + 1][2]; h[7] = (bf16)va[2 * j + 1][3];         \
            *(bf16x8*)(&As[0][0] + (size_t)row * 64 +                             \
                       (size_t)(g ^ (row & 7)) * 8) = h;                          \
        }                                                                         \
        /* A-prefetch for tile KT+1 (8 loads, newer than B) */                    \
        A_PREFETCH((KT) + 1);                                                     \
        /* barrier-1: drain exactly B (oldest 4 of 12) + LDS writes */            \
        asm volatile("s_waitcnt vmcnt(8) lgkmcnt(0)" ::: "memory");               \
        __builtin_amdgcn_s_barrier();                                             \
        asm volatile("" ::: "memory");                                            \
        /* MFMA region */                                                         \
        _Pragma("unroll") for (int kk = 0; kk < 2; ++kk) {                        \
            const int ga = kk ? ga1 : ga0;                                        \
            bf16x8 a[4], b[4];                                                    \
            _Pragma("unroll") for (int m = 0; m < 4; ++m)                         \
                a[m] = *(const bf16x8*)(&As[0][0] + (arow_l + m * 16) * 64 + ga); \
            _Pragma("unroll") for (int n = 0; n < 4; ++n)                         \
                b[n] = *(const bf16x8*)(&Bs[0][0] + (brow_l + n * 16) * 64 + ga); \
            _Pragma("unroll") for (int m = 0; m < 4; ++m)                         \
                _Pragma("unroll") for (int n = 0; n < 4; ++n)                     \
                    acc[m][n] = __builtin_amdgcn_mfma_f32_16x16x32_bf16(          \
                        a[m], b[n], acc[m][n], 0, 0, 0);                          \
        }                                                                         \
        /* barrier-2: lgkm only — A-prefetch survives */                          \
        asm volatile("s_waitcnt lgkmcnt(0)" ::: "memory");                        \
        __builtin_amdgcn_s_barrier();                                             \
        asm volatile("" ::: "memory");                                            \
    } while (0)

    // ---- prologue: load tile 0's fp32 A into va ----
    A_PREFETCH(0);

    // ---- main loop: 32 K-tiles ----
    for (int kt = 0; kt < 32; ++kt) {
        TILE_ITER(kt);   // kt=31 prefetches tile 0 (unused)
    }

    // ---- fused epilogue: GroupNorm (group == wave's 64-col span) + row min ----
    float gw[4], gb[4];
#pragma unroll
    for (int n = 0; n < 4; ++n) {
        int col = bcol + wc * 64 + n * 16 + r;
        gw[n] = gnw[col];
        gb[n] = gnb[col];
    }
#pragma unroll
    for (int m = 0; m < 4; ++m) {
#pragma unroll
        for (int j = 0; j < 4; ++j) {
            float s = 0.f, ss = 0.f;
#pragma unroll
            for (int n = 0; n < 4; ++n) {
                float v = acc[m][n][j];
                s += v; ss += v * v;
            }
#pragma unroll
            for (int d = 1; d < 16; d <<= 1) {
                s += __shfl_xor(s, d);
                ss += __shfl_xor(ss, d);
            }
            float mean = s * (1.f / 64.f);
            float var = ss * (1.f / 64.f) - mean * mean;
            float rstd = rsqrtf(var + EPSV);
            float mn = 3.4e38f;
#pragma unroll
            for (int n = 0; n < 4; ++n) {
                float y = (acc[m][n][j] - mean) * rstd * gw[n] + gb[n];
                mn = fminf(mn, y);
            }
#pragma unroll
            for (int d = 1; d < 16; d <<= 1) mn = fminf(mn, __shfl_xor(mn, d));
            if (r == 0)
                atomicMin(&rowmin[brow + wr * 64 + m * 16 + q * 4 + j], fenc(mn));
        }
    }
}

// out[m][n] = dec(rowmin[m]) + bias[n]
__global__ void bcast_kernel(const unsigned* __restrict__ rowmin,
                             const float* __restrict__ bias,
                             float* __restrict__ out) {
    const long total4 = (long)M_DIM * N_DIM / 4;
    long i = (long)blockIdx.x * blockDim.x + threadIdx.x;
    long stride = (long)gridDim.x * blockDim.x;
    for (; i < total4; i += stride) {
        int mrow = (int)(i >> 8);  // N/4 = 256 float4 per row
        int n4 = (int)(i & 255);
        float rm = fdec(rowmin[mrow]);
        f32x4 b = ((const f32x4*)bias)[n4];
        f32x4 o;
        o[0] = rm + b[0]; o[1] = rm + b[1]; o[2] = rm + b[2]; o[3] = rm + b[3];
        ((f32x4*)out)[i] = o;
    }
}

extern "C" void kernel_launch(void* const* d_in, const int* in_sizes, int n_in,
                              void* d_out, int out_size, void* d_ws, size_t ws_size,
                              hipStream_t stream) {
    const float* x = (const float*)d_in[0];
    const float* w = (const float*)d_in[1];
    const float* gnw = (const float*)d_in[2];
    const float* gnb = (const float*)d_in[3];
    const float* bias = (const float*)d_in[4];

    unsigned char* ws = (unsigned char*)d_ws;
    unsigned* rowmin = (unsigned*)ws;                          // 256 KB
    bf16* wb = (bf16*)(ws + (size_t)M_DIM * 4);                // 4 MB

    (void)hipMemsetAsync(rowmin, 0xFF, (size_t)M_DIM * 4, stream);  // +inf in encoding
    cvt_kernel<<<512, 256, 0, stream>>>(w, wb, (long)N_DIM * K_DIM / 4);

    gemm_fused<<<dim3(4096), 256, 0, stream>>>(x, wb, gnw, gnb, rowmin);

    bcast_kernel<<<2048, 256, 0, stream>>>(rowmin, bias, (float*)d_out);
}